// Round 1
// 774.335 us; speedup vs baseline: 1.0486x; 1.0486x over previous
//
#include <hip/hip_runtime.h>
#include <hip/hip_bf16.h>
#include <math.h>

#define Ntok 8192
#define Dm   1024
#define Hm   2048
#define NE   8

typedef __hip_bfloat16 bf16;
typedef __attribute__((ext_vector_type(8))) short short8;
typedef __attribute__((ext_vector_type(4))) float f32x4;

static __device__ __forceinline__ float b2f(bf16 v){ return __bfloat162float(v); }
static __device__ __forceinline__ bf16  f2b(float v){ return __float2bfloat16(v); }

// async global->LDS, 16B per lane; LDS dest must be wave-uniform base (lane i lands at base + i*16)
static __device__ __forceinline__ void gl2lds16(const bf16* g, bf16* l) {
    __builtin_amdgcn_global_load_lds(
        (const __attribute__((address_space(1))) unsigned*)(const void*)g,
        (__attribute__((address_space(3))) unsigned*)(void*)l, 16, 0, 0);
}

// ---------------- dtype detect: fp32 data has fp32-exponent <200; bf16-pairs >=~240 ----------------
__global__ void detect_kernel(const unsigned* __restrict__ xw, int* dtf)
{
    unsigned w = xw[threadIdx.x];
    int ex = (w >> 23) & 0xff;
    unsigned long long m = __ballot(ex < 200);
    if (threadIdx.x == 0) *dtf = (__popcll(m) > 32) ? 1 : 0;
}

// ---------------- x -> bf16 (xb lives in d_out scratch; dead before combine rewrites y) ----------------
__global__ void xconv_kernel(const void* __restrict__ xv, const int* __restrict__ dtf,
                             bf16* __restrict__ xb)
{
    int gid = blockIdx.x * 256 + threadIdx.x;
    size_t i = (size_t)gid * 8;
    if (*dtf) {
        const float* x = (const float*)xv + i;
        float4 v0 = *(const float4*)x;
        float4 v1 = *(const float4*)(x + 4);
        bf16 t[8] = { f2b(v0.x), f2b(v0.y), f2b(v0.z), f2b(v0.w),
                      f2b(v1.x), f2b(v1.y), f2b(v1.z), f2b(v1.w) };
        *(uint4*)(xb + i) = *(uint4*)t;
    } else {
        *(uint4*)(xb + i) = *(const uint4*)((const bf16*)xv + i);
    }
}

// ---------------- gate: softmax + top-2 routing ----------------
__global__ void gate_kernel(const void* __restrict__ xv, const void* __restrict__ wgv,
                            const int* __restrict__ dtf,
                            int* cnt, float* Psum, float* wts, int* idx_buf)
{
    int fp32 = *dtf;
    int lane = threadIdx.x & 63;
    int wv   = threadIdx.x >> 6;
    int n    = blockIdx.x * 4 + wv;

    float acc[NE];
    #pragma unroll
    for (int e = 0; e < NE; e++) acc[e] = 0.f;

    if (fp32) {
        const float* xr = (const float*)xv + (size_t)n * Dm;
        const float* Wg = (const float*)wgv;
        #pragma unroll
        for (int i = 0; i < 16; i++) {
            float xval = xr[lane + 64*i];
            #pragma unroll
            for (int e = 0; e < NE; e++) acc[e] += xval * Wg[e*Dm + lane + 64*i];
        }
    } else {
        const bf16* xr = (const bf16*)xv + (size_t)n * Dm;
        const bf16* Wg = (const bf16*)wgv;
        #pragma unroll
        for (int i = 0; i < 16; i++) {
            float xval = b2f(xr[lane + 64*i]);
            #pragma unroll
            for (int e = 0; e < NE; e++) acc[e] += xval * b2f(Wg[e*Dm + lane + 64*i]);
        }
    }
    #pragma unroll
    for (int e = 0; e < NE; e++) {
        float v = acc[e];
        #pragma unroll
        for (int off = 32; off > 0; off >>= 1) v += __shfl_xor(v, off);
        acc[e] = v;
    }
    float mx = acc[0];
    #pragma unroll
    for (int e = 1; e < NE; e++) mx = fmaxf(mx, acc[e]);
    float p[NE]; float s = 0.f;
    #pragma unroll
    for (int e = 0; e < NE; e++) { p[e] = expf(acc[e] - mx); s += p[e]; }
    float inv = 1.f / s;
    #pragma unroll
    for (int e = 0; e < NE; e++) p[e] *= inv;
    int e0 = 0;
    #pragma unroll
    for (int e = 1; e < NE; e++) if (p[e] > p[e0]) e0 = e;
    int e1 = (e0 == 0) ? 1 : 0;
    #pragma unroll
    for (int e = 0; e < NE; e++) if (e != e0 && p[e] > p[e1]) e1 = e;

    if (lane < NE) atomicAdd(Psum + lane, p[lane]);
    if (lane == 0) {
        int p0 = atomicAdd(cnt + e0, 1);
        idx_buf[e0*Ntok + p0] = n;              // k=0
        int p1 = atomicAdd(cnt + e1, 1);
        idx_buf[e1*Ntok + p1] = n | 0x10000;    // k=1 flag in bit 16
        wts[2*n]   = p[e0];
        wts[2*n+1] = p[e1];
    }
}

// ---------------- aux loss + per-expert dense-slot offsets ----------------
__global__ void aux_kernel(const int* __restrict__ cnt, const float* __restrict__ Psum,
                           const int* __restrict__ dtf, int* __restrict__ offs,
                           void* __restrict__ out)
{
    if (threadIdx.x == 0) {
        float s = 0.f; int a = 0;
        for (int e = 0; e < NE; e++) {
            offs[e] = a; a += cnt[e];
            s += (float)cnt[e] * Psum[e];
        }
        float aux = 0.08f * s / (16384.f * 8192.f);
        if (*dtf) ((float*)out)[(size_t)Ntok * Dm] = aux;
        else      ((bf16*)out)[(size_t)Ntok * Dm] = f2b(aux);
    }
}

// ---------------- transpose (two sources, same shape): src[R][C] -> dst[C][R] bf16, 64x64 tiles ----------------
__global__ void transpose2_kernel(const void* __restrict__ sA, const void* __restrict__ sB,
                                  bf16* __restrict__ dA, bf16* __restrict__ dB,
                                  int R, int C, const int* __restrict__ dtf)
{
    __shared__ bf16 t[64][68];
    int mat = blockIdx.z >> 3, e = blockIdx.z & 7;
    const void* src = mat ? sB : sA;
    bf16* dst = mat ? dB : dA;
    size_t base = (size_t)e * R * C;
    int c0 = blockIdx.x * 64, r0 = blockIdx.y * 64;
    int tid = threadIdx.x;
    int lr = tid >> 4;            // 0..15
    int lc = (tid & 15) * 4;      // 0..60

    if (*dtf) {
        const float* s = (const float*)src + base;
        #pragma unroll
        for (int i = 0; i < 4; i++) {
            float4 v = *(const float4*)(s + (size_t)(r0 + lr + 16*i) * C + c0 + lc);
            t[lr+16*i][lc+0] = f2b(v.x); t[lr+16*i][lc+1] = f2b(v.y);
            t[lr+16*i][lc+2] = f2b(v.z); t[lr+16*i][lc+3] = f2b(v.w);
        }
    } else {
        const bf16* s = (const bf16*)src + base;
        #pragma unroll
        for (int i = 0; i < 4; i++) {
            bf16 v[4];
            *(uint2*)v = *(const uint2*)(s + (size_t)(r0 + lr + 16*i) * C + c0 + lc);
            t[lr+16*i][lc+0] = v[0]; t[lr+16*i][lc+1] = v[1];
            t[lr+16*i][lc+2] = v[2]; t[lr+16*i][lc+3] = v[3];
        }
    }
    __syncthreads();
    int oc = tid >> 2;            // 0..63  (output row = source column)
    int os = tid & 3;             // 16-element segment
    bf16 ov[16];
    #pragma unroll
    for (int j = 0; j < 16; j++) ov[j] = t[os*16 + j][oc];
    bf16* dp = dst + base + (size_t)(c0 + oc) * R + r0 + os*16;
    *(uint4*)dp       = *(uint4*)ov;
    *(uint4*)(dp + 8) = *(uint4*)(ov + 8);
}

// ---------------- ffn1: h = silu(xg@W1+b1) * (xg@W3+b3) ----------------
// m97-structure: 128 tokens x 64 H-cols (per B matrix), BK=32, 4 waves (2x2),
// all tiles staged via global_load_lds (x pre-converted to bf16).
__global__ __launch_bounds__(256) void ffn1_kernel(
    const bf16* __restrict__ xb, const bf16* __restrict__ w1t, const bf16* __restrict__ w3t,
    const void* __restrict__ b1v, const void* __restrict__ b3v, const int* __restrict__ dtf,
    const int* __restrict__ cnt, const int* __restrict__ offs,
    const int* __restrict__ idx_buf, bf16* __restrict__ hbuf)
{
    int e = blockIdx.z;
    int c = cnt[e];
    int m0 = blockIdx.y * 128;
    if (m0 >= c) return;
    int h0 = blockIdx.x * 64;
    int fp32 = *dtf;
    int slot0 = offs[e] + m0;

    __shared__ __align__(16) bf16 aL[128][32];
    __shared__ __align__(16) bf16 bL1[64][32];
    __shared__ __align__(16) bf16 bL3[64][32];
    __shared__ int tk[128];

    int tid = threadIdx.x;
    if (tid < 128) {
        int m = m0 + tid; if (m > c - 1) m = c - 1;
        tk[tid] = idx_buf[e*Ntok + m] & 0xffff;
    }
    __syncthreads();

    int lane = tid & 63, w = tid >> 6;
    int mrow = lane & 15, kg = lane >> 4;
    int wr = w >> 1, wc = w & 1;

    const bf16* w1e = w1t + (size_t)e * Hm * Dm;
    const bf16* w3e = w3t + (size_t)e * Hm * Dm;

    // A staging: wave w covers rows [32w, 32w+32) in two 16-row issues; row = 64B = 4 lanes
    int ch = lane & 3;
    int rA = w*32 + (lane >> 2);
    const bf16* gA0 = xb + (size_t)tk[rA]      * Dm + ch*8;
    const bf16* gA1 = xb + (size_t)tk[rA + 16] * Dm + ch*8;
    bf16* lA0 = &aL[w*32][0];
    bf16* lA1 = &aL[w*32 + 16][0];
    // B staging: wave w covers rows [16w, 16w+16), one issue per matrix
    int rB = h0 + w*16 + (lane >> 2);
    const bf16* gB1 = w1e + (size_t)rB * Dm + ch*8;
    const bf16* gB3 = w3e + (size_t)rB * Dm + ch*8;
    bf16* lB1 = &bL1[w*16][0];
    bf16* lB3 = &bL3[w*16][0];

    f32x4 acc1[4][2], acc3[4][2];
    f32x4 z = {0.f, 0.f, 0.f, 0.f};
    #pragma unroll
    for (int ms = 0; ms < 4; ms++)
        #pragma unroll
        for (int ns = 0; ns < 2; ns++) { acc1[ms][ns] = z; acc3[ms][ns] = z; }

    for (int k0 = 0; k0 < Dm; k0 += 32) {
        gl2lds16(gA0, lA0); gl2lds16(gA1, lA1);
        gl2lds16(gB1, lB1); gl2lds16(gB3, lB3);
        gA0 += 32; gA1 += 32; gB1 += 32; gB3 += 32;
        __syncthreads();

        short8 af[4], b1f[2], b3f[2];
        #pragma unroll
        for (int ms = 0; ms < 4; ms++)
            af[ms] = *(const short8*)&aL[wr*64 + ms*16 + mrow][kg*8];
        #pragma unroll
        for (int ns = 0; ns < 2; ns++) {
            b1f[ns] = *(const short8*)&bL1[wc*32 + ns*16 + mrow][kg*8];
            b3f[ns] = *(const short8*)&bL3[wc*32 + ns*16 + mrow][kg*8];
        }
        #pragma unroll
        for (int ms = 0; ms < 4; ms++)
            #pragma unroll
            for (int ns = 0; ns < 2; ns++) {
                acc1[ms][ns] = __builtin_amdgcn_mfma_f32_16x16x32_bf16(af[ms], b1f[ns], acc1[ms][ns], 0, 0, 0);
                acc3[ms][ns] = __builtin_amdgcn_mfma_f32_16x16x32_bf16(af[ms], b3f[ns], acc3[ms][ns], 0, 0, 0);
            }
        __syncthreads();
    }

    #pragma unroll
    for (int ns = 0; ns < 2; ns++) {
        int col = h0 + wc*32 + ns*16 + mrow;
        float bb1 = fp32 ? ((const float*)b1v)[e*Hm + col] : b2f(((const bf16*)b1v)[e*Hm + col]);
        float bb3 = fp32 ? ((const float*)b3v)[e*Hm + col] : b2f(((const bf16*)b3v)[e*Hm + col]);
        #pragma unroll
        for (int ms = 0; ms < 4; ms++) {
            #pragma unroll
            for (int r = 0; r < 4; r++) {
                int row = wr*64 + ms*16 + kg*4 + r;
                if (m0 + row < c) {
                    float v1 = acc1[ms][ns][r] + bb1;
                    float v3 = acc3[ms][ns][r] + bb3;
                    float hv = (v1 / (1.f + expf(-v1))) * v3;   // silu(v1)*v3
                    hbuf[(size_t)(slot0 + row)*Hm + col] = f2b(hv);
                }
            }
        }
    }
}

// ---------------- ffn2: out_slot = h @ W2 + b2 (dense A, scattered output rows) ----------------
// m97-structure: 128 tokens x 128 D-cols, BK=32, 4 waves (2x2), acc[4][4] per wave.
__global__ __launch_bounds__(256) void ffn2_kernel(
    const bf16* __restrict__ hbuf, const bf16* __restrict__ w2t, const void* __restrict__ b2v,
    const int* __restrict__ dtf, const int* __restrict__ cnt, const int* __restrict__ offs,
    const int* __restrict__ idx_buf, bf16* __restrict__ outs)
{
    int e = blockIdx.z;
    int c = cnt[e];
    int m0 = blockIdx.y * 128;
    if (m0 >= c) return;
    int d0 = blockIdx.x * 128;
    int fp32 = *dtf;
    int slot0 = offs[e] + m0;

    __shared__ __align__(16) bf16 aL[128][32];
    __shared__ __align__(16) bf16 bL[128][32];
    __shared__ int rl[128];

    int tid = threadIdx.x;
    if (tid < 128) {
        int m = m0 + tid; if (m > c - 1) m = c - 1;
        int v = idx_buf[e*Ntok + m];
        rl[tid] = 2*(v & 0xffff) + (v >> 16);
    }
    __syncthreads();

    int lane = tid & 63, w = tid >> 6;
    int mrow = lane & 15, kg = lane >> 4;
    int wr = w >> 1, wc = w & 1;

    const bf16* w2e = w2t + (size_t)e * Dm * Hm;

    int ch = lane & 3;
    int rloc = w*32 + (lane >> 2);
    int s0r = rloc;      if (s0r > c - 1) s0r = c - 1;
    int s1r = rloc + 16; if (s1r > c - 1) s1r = c - 1;
    const bf16* gA0 = hbuf + (size_t)(slot0 + s0r) * Hm + ch*8;
    const bf16* gA1 = hbuf + (size_t)(slot0 + s1r) * Hm + ch*8;
    bf16* lA0 = &aL[w*32][0];
    bf16* lA1 = &aL[w*32 + 16][0];
    const bf16* gB0 = w2e + (size_t)(d0 + rloc)      * Hm + ch*8;
    const bf16* gB1 = w2e + (size_t)(d0 + rloc + 16) * Hm + ch*8;
    bf16* lB0 = &bL[w*32][0];
    bf16* lB1 = &bL[w*32 + 16][0];

    f32x4 acc[4][4];
    f32x4 z = {0.f, 0.f, 0.f, 0.f};
    #pragma unroll
    for (int ms = 0; ms < 4; ms++)
        #pragma unroll
        for (int ns = 0; ns < 4; ns++) acc[ms][ns] = z;

    for (int k0 = 0; k0 < Hm; k0 += 32) {
        gl2lds16(gA0, lA0); gl2lds16(gA1, lA1);
        gl2lds16(gB0, lB0); gl2lds16(gB1, lB1);
        gA0 += 32; gA1 += 32; gB0 += 32; gB1 += 32;
        __syncthreads();

        short8 af[4], bfr[4];
        #pragma unroll
        for (int ms = 0; ms < 4; ms++)
            af[ms] = *(const short8*)&aL[wr*64 + ms*16 + mrow][kg*8];
        #pragma unroll
        for (int ns = 0; ns < 4; ns++)
            bfr[ns] = *(const short8*)&bL[wc*64 + ns*16 + mrow][kg*8];
        #pragma unroll
        for (int ms = 0; ms < 4; ms++)
            #pragma unroll
            for (int ns = 0; ns < 4; ns++)
                acc[ms][ns] = __builtin_amdgcn_mfma_f32_16x16x32_bf16(af[ms], bfr[ns], acc[ms][ns], 0, 0, 0);
        __syncthreads();
    }

    #pragma unroll
    for (int ns = 0; ns < 4; ns++) {
        int col = d0 + wc*64 + ns*16 + mrow;
        float bb2 = fp32 ? ((const float*)b2v)[e*Dm + col] : b2f(((const bf16*)b2v)[e*Dm + col]);
        #pragma unroll
        for (int ms = 0; ms < 4; ms++) {
            #pragma unroll
            for (int r = 0; r < 4; r++) {
                int row = wr*64 + ms*16 + kg*4 + r;
                if (m0 + row < c)
                    outs[(size_t)rl[row]*Dm + col] = f2b(acc[ms][ns][r] + bb2);
            }
        }
    }
}

// ---------------- combine: y[n] = w0*out[2n] + w1*out[2n+1] ----------------
__global__ void combine_kernel(const bf16* __restrict__ outs, const float* __restrict__ wts,
                               const int* __restrict__ dtf, void* __restrict__ yv)
{
    int gid = blockIdx.x * 256 + threadIdx.x;
    int n = gid >> 7;
    int j = (gid & 127) * 8;
    float w0 = wts[2*n], w1 = wts[2*n+1];
    bf16 ra[8], rb[8];
    *(uint4*)ra = *(const uint4*)(outs + (size_t)(2*n)   * Dm + j);
    *(uint4*)rb = *(const uint4*)(outs + (size_t)(2*n+1) * Dm + j);
    float o[8];
    #pragma unroll
    for (int t = 0; t < 8; t++)
        o[t] = w0 * b2f(ra[t]) + w1 * b2f(rb[t]);
    if (*dtf) {
        float* y = (float*)yv + (size_t)n * Dm + j;
        *(float4*)y       = make_float4(o[0], o[1], o[2], o[3]);
        *(float4*)(y + 4) = make_float4(o[4], o[5], o[6], o[7]);
    } else {
        bf16 ro[8];
        #pragma unroll
        for (int t = 0; t < 8; t++) ro[t] = f2b(o[t]);
        *(uint4*)((bf16*)yv + (size_t)n * Dm + j) = *(uint4*)ro;
    }
}

extern "C" void kernel_launch(void* const* d_in, const int* in_sizes, int n_in,
                              void* d_out, int out_size, void* d_ws, size_t ws_size,
                              hipStream_t stream)
{
    (void)in_sizes; (void)n_in; (void)out_size; (void)ws_size;
    const void* x  = d_in[0];
    const void* Wg = d_in[1];
    const void* W1 = d_in[2];
    const void* b1 = d_in[3];
    const void* W2 = d_in[4];
    const void* b2 = d_in[5];
    const void* W3 = d_in[6];
    const void* b3 = d_in[7];

    char* ws = (char*)d_ws;
    int*   cnt  = (int*)ws;                      // [0,32)
    int*   dtf  = (int*)(ws + 64);               // dtype flag
    float* Psum = (float*)(ws + 256);            // [256,288)
    int*   offs = (int*)(ws + 512);              // [512,544)
    float* wts  = (float*)(ws + 4096);           // 64 KB -> 69632
    int*   idx  = (int*)(ws + 69632);            // 256 KB -> 331776
    bf16* bufA  = (bf16*)(ws + 331776);          // 32 MiB (w1t, then w2t)
    bf16* bufB  = (bf16*)(ws + 33886208);        // 32 MiB (w3t, then outs)
    bf16* hbuf  = (bf16*)(ws + 67440640);        // 64 MiB -> ends 134549504 (~128.3 MiB total)
    bf16* outs  = bufB;
    // xb (bf16 copy of x, 16 MiB) lives in d_out scratch: dead before combine
    // rewrites y; aux scalar sits at element Ntok*Dm (byte 16 MiB bf16 / 32 MiB fp32), untouched.
    bf16* xb    = (bf16*)d_out;

    hipMemsetAsync(d_ws, 0, 4096, stream);
    detect_kernel<<<1, 64, 0, stream>>>((const unsigned*)x, dtf);
    xconv_kernel<<<(Ntok*Dm/8)/256, 256, 0, stream>>>(x, dtf, xb);
    gate_kernel<<<Ntok/4, 256, 0, stream>>>(x, Wg, dtf, cnt, Psum, wts, idx);
    aux_kernel<<<1, 64, 0, stream>>>(cnt, Psum, dtf, offs, d_out);
    // W1,W3: [D][H] -> [H][D]
    transpose2_kernel<<<dim3(Hm/64, Dm/64, 16), 256, 0, stream>>>(W1, W3, bufA, bufB, Dm, Hm, dtf);
    ffn1_kernel<<<dim3(Hm/64, Ntok/128, NE), 256, 0, stream>>>(xb, bufA, bufB, b1, b3, dtf, cnt, offs, idx, hbuf);
    // W2: [H][D] -> [D][H]  (into bufA, w1t dead)
    transpose2_kernel<<<dim3(Dm/64, Hm/64, 8), 256, 0, stream>>>(W2, W2, bufA, bufA, Hm, Dm, dtf);
    ffn2_kernel<<<dim3(Dm/128, Ntok/128, NE), 256, 0, stream>>>(hbuf, bufA, b2, dtf, cnt, offs, idx, outs);
    combine_kernel<<<(Ntok*Dm/8)/256, 256, 0, stream>>>(outs, wts, dtf, d_out);
}